// Round 18
// baseline (1485.054 us; speedup 1.0000x reference)
//
#include <hip/hip_runtime.h>
#include <hip/hip_bf16.h>
#include <math.h>

// ---------------------------------------------------------------------------
// Round 18: attn re-tiled to 2 waves x 32 q-rows (128-thr block) — each K/V
// fragment ds_read feeds 2 MFMAs (was 1): per-block LDS ops 172 -> ~104 at
// same MFMA count/grid/balance-swizzle. All else = round 17 (proven).
// B=4 S=1024 D=1024 H=8 Dh=128 F=2048 L=4 V=32000
// ---------------------------------------------------------------------------

#define D_MODEL 1024
#define SEQ     1024
#define BATCH   4
#define NHEAD   8
#define HDIM    128
#define FFN     2048
#define NLAYER  4
#define VOCAB   32000
#define MROWS   (BATCH*SEQ)   // 4096

typedef unsigned short ushort_t;
typedef __attribute__((ext_vector_type(8))) short s16x8;   // 8 bf16 = 4 VGPRs
typedef __attribute__((ext_vector_type(4))) float f32x4;

__device__ __forceinline__ ushort_t f2bf(float f) {
    union { float f; unsigned int u; } c; c.f = f;
    unsigned int u = c.u;
    unsigned int r = (u + 0x7FFFu + ((u >> 16) & 1u)) >> 16;
    return (ushort_t)r;
}
__device__ __forceinline__ float bf2f(ushort_t u) {
    union { unsigned int u; float f; } c; c.u = ((unsigned int)u) << 16; return c.f;
}

__device__ __forceinline__ void gload16(const void* g, void* l) {
    __builtin_amdgcn_global_load_lds(
        (const __attribute__((address_space(1))) unsigned int*)g,
        (__attribute__((address_space(3))) unsigned int*)l, 16, 0, 0);
}

__device__ __forceinline__ float gelu_exact(float x) {
    return 0.5f * x * (1.0f + erff(x * 0.70710678118654752f));
}

// ---------------- embedding gather (fp32 residual stream) ----------------
__global__ __launch_bounds__(256) void embed_kernel(
    const int* __restrict__ tokens, const float* __restrict__ emb,
    float* __restrict__ X)
{
    int row = blockIdx.x;
    int t = tokens[row];
    const float4* src = (const float4*)(emb + (size_t)t * D_MODEL);
    float4* dst = (float4*)(X + (size_t)row * D_MODEL);
    dst[threadIdx.x] = src[threadIdx.x];
}

// ---------------- layernorm: fp32 in -> bf16 out ----------------
__global__ __launch_bounds__(256) void ln_kernel(
    const float* __restrict__ X, const float* __restrict__ g,
    const float* __restrict__ b, ushort_t* __restrict__ Y)
{
    __shared__ float red[8];
    int row = blockIdx.x;
    const float4* x4 = (const float4*)(X + (size_t)row * D_MODEL);
    float4 v = x4[threadIdx.x];
    float s  = v.x + v.y + v.z + v.w;
    float ss = v.x*v.x + v.y*v.y + v.z*v.z + v.w*v.w;
    #pragma unroll
    for (int o = 32; o > 0; o >>= 1) { s += __shfl_down(s, o); ss += __shfl_down(ss, o); }
    int wid = threadIdx.x >> 6;
    if ((threadIdx.x & 63) == 0) { red[wid] = s; red[wid + 4] = ss; }
    __syncthreads();
    float tot  = red[0] + red[1] + red[2] + red[3];
    float tot2 = red[4] + red[5] + red[6] + red[7];
    float mu  = tot * (1.0f / D_MODEL);
    float var = tot2 * (1.0f / D_MODEL) - mu * mu;
    float r = rsqrtf(var + 1e-5f);
    const float4* g4 = (const float4*)g;
    const float4* b4 = (const float4*)b;
    float4 gv = g4[threadIdx.x], bv = b4[threadIdx.x];
    ushort4 o;
    o.x = f2bf((v.x - mu) * r * gv.x + bv.x);
    o.y = f2bf((v.y - mu) * r * gv.y + bv.y);
    o.z = f2bf((v.z - mu) * r * gv.z + bv.z);
    o.w = f2bf((v.w - mu) * r * gv.w + bv.w);
    ((ushort4*)(Y + (size_t)row * D_MODEL))[threadIdx.x] = o;
}

// ---------------- weight fp32 [K][N] -> bf16 transposed [N][K] -------------
__global__ __launch_bounds__(256) void wconv(
    const float* __restrict__ W, ushort_t* __restrict__ Wt, int K, int N)
{
    __shared__ float t[32][33];
    const float* Wl = W + (size_t)blockIdx.z * K * N;
    ushort_t* Wtl = Wt + (size_t)blockIdx.z * K * N;
    int k0 = blockIdx.y * 32, n0 = blockIdx.x * 32;
    int tid = threadIdx.x;
    int r = tid >> 3, c4 = (tid & 7) * 4;
    float4 v = *(const float4*)(Wl + (size_t)(k0 + r) * N + n0 + c4);
    t[r][c4+0] = v.x; t[r][c4+1] = v.y; t[r][c4+2] = v.z; t[r][c4+3] = v.w;
    __syncthreads();
    ushort4 o;
    o.x = f2bf(t[c4+0][r]); o.y = f2bf(t[c4+1][r]);
    o.z = f2bf(t[c4+2][r]); o.w = f2bf(t[c4+3][r]);
    *(ushort4*)(Wtl + (size_t)(n0 + r) * K + k0 + c4) = o;
}

// ---------------- 128x128 pipelined counted-vmcnt GEMM + T2 (layers) -------
template<int ACT, int BETA, int OBF>
__global__ __launch_bounds__(256) void gemm_mid(
    const ushort_t* __restrict__ A, const ushort_t* __restrict__ Bt,
    const float* __restrict__ bias, float* __restrict__ Cf,
    ushort_t* __restrict__ Cb, int M, int N, int K)
{
    __shared__ __align__(16) ushort_t As[2][128 * 64];   // 32 KB
    __shared__ __align__(16) ushort_t Bs[2][128 * 64];   // 32 KB
    int tid = threadIdx.x, lane = tid & 63, w = tid >> 6;
    int wm = w >> 1, wn = w & 1;
    int m0 = blockIdx.x * 128, n0 = blockIdx.y * 128;
    int lr = lane & 15, kg = lane >> 4;
    const int NKT = K / 64;

    f32x4 acc[4][4] = {};

    int srow = w * 8 + (lane >> 3);                       // 0..31
    int scol = (((lane & 7) ^ ((lane >> 3) & 7))) * 8;    // T2 pre-swizzled src

    int rsw = lr & 7;
    int ch0 = (kg    ) ^ rsw;
    int ch1 = (kg + 4) ^ rsw;

#define STAGE_A(db, ht, ktile) do { \
    const ushort_t* s_ = A + (size_t)(m0 + (ht) * 64 + srow) * K + (size_t)(ktile) * 64 + scol; \
    gload16(s_,                  &As[db][((ht) * 64 + w * 8) * 64]); \
    gload16(s_ + (size_t)32 * K, &As[db][((ht) * 64 + 32 + w * 8) * 64]); \
} while (0)
#define STAGE_B(db, ht, ktile) do { \
    const ushort_t* s_ = Bt + (size_t)(n0 + (ht) * 64 + srow) * K + (size_t)(ktile) * 64 + scol; \
    gload16(s_,                  &Bs[db][((ht) * 64 + w * 8) * 64]); \
    gload16(s_ + (size_t)32 * K, &Bs[db][((ht) * 64 + 32 + w * 8) * 64]); \
} while (0)
#define SBAR() do { __builtin_amdgcn_sched_barrier(0); \
    __builtin_amdgcn_s_barrier(); __builtin_amdgcn_sched_barrier(0); } while (0)

    STAGE_A(0, 0, 0); STAGE_A(0, 1, 0); STAGE_B(0, 0, 0); STAGE_B(0, 1, 0);
    STAGE_A(1, 0, 1);
    asm volatile("s_waitcnt vmcnt(2)" ::: "memory");
    SBAR();

    for (int kt = 0; kt < NKT; ++kt) {
        int d = kt & 1, dn = d ^ 1;
        const ushort_t* pa0 = &As[d][(wm * 64 + lr) * 64 + ch0 * 8];
        const ushort_t* pa1 = &As[d][(wm * 64 + lr) * 64 + ch1 * 8];
        const ushort_t* pb0 = &Bs[d][(wn * 64 + lr) * 64 + ch0 * 8];
        const ushort_t* pb1 = &Bs[d][(wn * 64 + lr) * 64 + ch1 * 8];
        s16x8 a[4][2], b[4][2];

        #pragma unroll
        for (int mi = 0; mi < 4; ++mi) {
            a[mi][0] = *(const s16x8*)(pa0 + mi * 1024);
            a[mi][1] = *(const s16x8*)(pa1 + mi * 1024);
        }
        #pragma unroll
        for (int ni = 0; ni < 4; ++ni) {
            b[ni][0] = *(const s16x8*)(pb0 + ni * 1024);
            b[ni][1] = *(const s16x8*)(pb1 + ni * 1024);
        }
        if (kt + 1 < NKT) STAGE_A(dn, 1, kt + 1);
        __builtin_amdgcn_sched_barrier(0);

        __builtin_amdgcn_s_setprio(1);
        #pragma unroll
        for (int mi = 0; mi < 2; ++mi)
            #pragma unroll
            for (int ni = 0; ni < 2; ++ni)
                #pragma unroll
                for (int kk = 0; kk < 2; ++kk)
                    acc[mi][ni] = __builtin_amdgcn_mfma_f32_16x16x32_bf16(
                        a[mi][kk], b[ni][kk], acc[mi][ni], 0, 0, 0);
        __builtin_amdgcn_s_setprio(0);
        __builtin_amdgcn_sched_barrier(0);
        if (kt + 1 < NKT) STAGE_B(dn, 0, kt + 1);
        __builtin_amdgcn_sched_barrier(0);

        __builtin_amdgcn_s_setprio(1);
        #pragma unroll
        for (int mi = 0; mi < 2; ++mi)
            #pragma unroll
            for (int ni = 2; ni < 4; ++ni)
                #pragma unroll
                for (int kk = 0; kk < 2; ++kk)
                    acc[mi][ni] = __builtin_amdgcn_mfma_f32_16x16x32_bf16(
                        a[mi][kk], b[ni][kk], acc[mi][ni], 0, 0, 0);
        __builtin_amdgcn_s_setprio(0);
        __builtin_amdgcn_sched_barrier(0);
        if (kt + 1 < NKT) STAGE_B(dn, 1, kt + 1);
        __builtin_amdgcn_sched_barrier(0);

        __builtin_amdgcn_s_setprio(1);
        #pragma unroll
        for (int mi = 2; mi < 4; ++mi)
            #pragma unroll
            for (int ni = 0; ni < 2; ++ni)
                #pragma unroll
                for (int kk = 0; kk < 2; ++kk)
                    acc[mi][ni] = __builtin_amdgcn_mfma_f32_16x16x32_bf16(
                        a[mi][kk], b[ni][kk], acc[mi][ni], 0, 0, 0);
        __builtin_amdgcn_s_setprio(0);

        asm volatile("s_waitcnt lgkmcnt(0)" ::: "memory");
        SBAR();
        if (kt + 2 < NKT) STAGE_A(d, 0, kt + 2);
        __builtin_amdgcn_sched_barrier(0);

        __builtin_amdgcn_s_setprio(1);
        #pragma unroll
        for (int mi = 2; mi < 4; ++mi)
            #pragma unroll
            for (int ni = 2; ni < 4; ++ni)
                #pragma unroll
                for (int kk = 0; kk < 2; ++kk)
                    acc[mi][ni] = __builtin_amdgcn_mfma_f32_16x16x32_bf16(
                        a[mi][kk], b[ni][kk], acc[mi][ni], 0, 0, 0);
        __builtin_amdgcn_s_setprio(0);

        if (kt + 2 < NKT) {
            asm volatile("s_waitcnt vmcnt(2)" ::: "memory");
        } else {
            asm volatile("s_waitcnt vmcnt(0)" ::: "memory");
        }
        SBAR();
    }
#undef STAGE_A
#undef STAGE_B
#undef SBAR

    #pragma unroll
    for (int mi = 0; mi < 4; ++mi) {
        int rbase = m0 + wm * 64 + mi * 16 + kg * 4;
        #pragma unroll
        for (int ni = 0; ni < 4; ++ni) {
            int col = n0 + wn * 64 + ni * 16 + lr;
            float bz = bias[col];
            f32x4 v = acc[mi][ni];
            #pragma unroll
            for (int j = 0; j < 4; ++j) {
                float x = v[j] + bz;
                if (ACT == 1) x = gelu_exact(x);
                size_t off = (size_t)(rbase + j) * N + col;
                if (OBF) {
                    Cb[off] = f2bf(x);
                } else {
                    if (BETA) x += Cf[off];
                    Cf[off] = x;
                }
            }
        }
    }
}

// ---------------- 256x256 pipelined counted-vmcnt GEMM + T2 (logits) -------
__global__ __launch_bounds__(512) void gemm_big(
    const ushort_t* __restrict__ A, const ushort_t* __restrict__ Bt,
    const float* __restrict__ bias, float* __restrict__ C,
    int M, int N, int K)
{
    __shared__ __align__(16) ushort_t As[2][256 * 64];   // 64 KB
    __shared__ __align__(16) ushort_t Bs[2][256 * 64];   // 64 KB
    int tid = threadIdx.x, lane = tid & 63, w = tid >> 6;
    int wm = w >> 2, wn = w & 3;
    int m0 = blockIdx.x * 256, n0 = blockIdx.y * 256;
    int lr = lane & 15, kg = lane >> 4;
    const int NKT = K / 64;

    f32x4 acc[8][4] = {};

    int srow = w * 8 + (lane >> 3);
    int scol = (((lane & 7) ^ ((lane >> 3) & 7))) * 8;

    int rsw = lr & 7;
    int ch0 = (kg    ) ^ rsw;
    int ch1 = (kg + 4) ^ rsw;

#define STAGE_A(db, ht, ktile) do { \
    const ushort_t* s_ = A + (size_t)(m0 + (ht) * 128 + srow) * K + (size_t)(ktile) * 64 + scol; \
    gload16(s_,                  &As[db][((ht) * 128 + w * 8) * 64]); \
    gload16(s_ + (size_t)64 * K, &As[db][((ht) * 128 + 64 + w * 8) * 64]); \
} while (0)
#define STAGE_B(db, ht, ktile) do { \
    const ushort_t* s_ = Bt + (size_t)(n0 + (ht) * 128 + srow) * K + (size_t)(ktile) * 64 + scol; \
    gload16(s_,                  &Bs[db][((ht) * 128 + w * 8) * 64]); \
    gload16(s_ + (size_t)64 * K, &Bs[db][((ht) * 128 + 64 + w * 8) * 64]); \
} while (0)
#define SBAR() do { __builtin_amdgcn_sched_barrier(0); \
    __builtin_amdgcn_s_barrier(); __builtin_amdgcn_sched_barrier(0); } while (0)

    STAGE_A(0, 0, 0); STAGE_A(0, 1, 0); STAGE_B(0, 0, 0); STAGE_B(0, 1, 0);
    STAGE_A(1, 0, 1);
    asm volatile("s_waitcnt vmcnt(2)" ::: "memory");
    SBAR();

    for (int kt = 0; kt < NKT; ++kt) {
        int d = kt & 1, dn = d ^ 1;
        const ushort_t* pa0 = &As[d][(wm * 128 + lr) * 64 + ch0 * 8];
        const ushort_t* pa1 = &As[d][(wm * 128 + lr) * 64 + ch1 * 8];
        const ushort_t* pb0 = &Bs[d][(wn * 64  + lr) * 64 + ch0 * 8];
        const ushort_t* pb1 = &Bs[d][(wn * 64  + lr) * 64 + ch1 * 8];
        s16x8 a03[4][2], a47[4][2], b01[2][2], b23[2][2];

        #pragma unroll
        for (int mi = 0; mi < 4; ++mi) {
            a03[mi][0] = *(const s16x8*)(pa0 + mi * 1024);
            a03[mi][1] = *(const s16x8*)(pa1 + mi * 1024);
        }
        #pragma unroll
        for (int ni = 0; ni < 2; ++ni) {
            b01[ni][0] = *(const s16x8*)(pb0 + ni * 1024);
            b01[ni][1] = *(const s16x8*)(pb1 + ni * 1024);
        }
        #pragma unroll
        for (int ni = 0; ni < 2; ++ni) {
            b23[ni][0] = *(const s16x8*)(pb0 + (2 + ni) * 1024);
            b23[ni][1] = *(const s16x8*)(pb1 + (2 + ni) * 1024);
        }
        #pragma unroll
        for (int mi = 0; mi < 4; ++mi) {
            a47[mi][0] = *(const s16x8*)(pa0 + (4 + mi) * 1024);
            a47[mi][1] = *(const s16x8*)(pa1 + (4 + mi) * 1024);
        }
        if (kt + 1 < NKT) STAGE_A(dn, 1, kt + 1);
        __builtin_amdgcn_sched_barrier(0);

        __builtin_amdgcn_s_setprio(1);
        #pragma unroll
        for (int mi = 0; mi < 4; ++mi)
            #pragma unroll
            for (int ni = 0; ni < 2; ++ni)
                #pragma unroll
                for (int kk = 0; kk < 2; ++kk)
                    acc[mi][ni] = __builtin_amdgcn_mfma_f32_16x16x32_bf16(
                        a03[mi][kk], b01[ni][kk], acc[mi][ni], 0, 0, 0);
        __builtin_amdgcn_s_setprio(0);
        __builtin_amdgcn_sched_barrier(0);
        if (kt + 1 < NKT) STAGE_B(dn, 0, kt + 1);
        __builtin_amdgcn_sched_barrier(0);

        __builtin_amdgcn_s_setprio(1);
        #pragma unroll
        for (int mi = 0; mi < 4; ++mi)
            #pragma unroll
            for (int ni = 0; ni < 2; ++ni)
                #pragma unroll
                for (int kk = 0; kk < 2; ++kk)
                    acc[mi][2 + ni] = __builtin_amdgcn_mfma_f32_16x16x32_bf16(
                        a03[mi][kk], b23[ni][kk], acc[mi][2 + ni], 0, 0, 0);
        __builtin_amdgcn_s_setprio(0);
        __builtin_amdgcn_sched_barrier(0);
        if (kt + 1 < NKT) STAGE_B(dn, 1, kt + 1);
        __builtin_amdgcn_sched_barrier(0);

        __builtin_amdgcn_s_setprio(1);
        #pragma unroll
        for (int mi = 0; mi < 4; ++mi)
            #pragma unroll
            for (int ni = 0; ni < 2; ++ni)
                #pragma unroll
                for (int kk = 0; kk < 2; ++kk)
                    acc[4 + mi][ni] = __builtin_amdgcn_mfma_f32_16x16x32_bf16(
                        a47[mi][kk], b01[ni][kk], acc[4 + mi][ni], 0, 0, 0);
        __builtin_amdgcn_s_setprio(0);

        asm volatile("s_waitcnt lgkmcnt(0)" ::: "memory");
        SBAR();
        if (kt + 2 < NKT) STAGE_A(d, 0, kt + 2);
        __builtin_amdgcn_sched_barrier(0);

        __builtin_amdgcn_s_setprio(1);
        #pragma unroll
        for (int mi = 0; mi < 4; ++mi)
            #pragma unroll
            for (int ni = 0; ni < 2; ++ni)
                #pragma unroll
                for (int kk = 0; kk < 2; ++kk)
                    acc[4 + mi][2 + ni] = __builtin_amdgcn_mfma_f32_16x16x32_bf16(
                        a47[mi][kk], b23[ni][kk], acc[4 + mi][2 + ni], 0, 0, 0);
        __builtin_amdgcn_s_setprio(0);

        if (kt + 2 < NKT) {
            asm volatile("s_waitcnt vmcnt(2)" ::: "memory");
        } else {
            asm volatile("s_waitcnt vmcnt(0)" ::: "memory");
        }
        SBAR();
    }
#undef STAGE_A
#undef STAGE_B
#undef SBAR

    #pragma unroll
    for (int mi = 0; mi < 8; ++mi) {
        int rbase = m0 + wm * 128 + mi * 16 + kg * 4;
        #pragma unroll
        for (int ni = 0; ni < 4; ++ni) {
            int col = n0 + wn * 64 + ni * 16 + lr;
            float bz = bias[col];
            f32x4 v = acc[mi][ni];
            #pragma unroll
            for (int j = 0; j < 4; ++j)
                C[(size_t)(rbase + j) * N + col] = v[j] + bz;
        }
    }
}

// ---------------- RoPE cos/sin table: [S][64] float2 (cos, sin) ------------
__global__ __launch_bounds__(64) void rope_table_kernel(float2* __restrict__ RT)
{
    int s = blockIdx.x, p = threadIdx.x;
    float inv = expf(-0.14391156831212788f * (float)p);   // 10000^(-p/64)
    float ang = (float)s * inv;
    float sn, c;
    sincosf(ang, &sn, &c);
    RT[s * 64 + p] = make_float2(c, sn);
}

// ---------------- RoPE: bf16 QKV -> bf16 Qb, Kb [B,H,S,Dh] (table) ---------
__global__ __launch_bounds__(256) void ropeq_kernel(
    const ushort_t* __restrict__ QKVb, const float2* __restrict__ RT,
    ushort_t* __restrict__ Qb, ushort_t* __restrict__ Kb)
{
    int m = blockIdx.x;
    int b = m >> 10, s = m & (SEQ - 1);
    const ushort_t* rowbase = QKVb + (size_t)m * (3 * D_MODEL);
    const float2* t2 = RT + s * 64;
    int tid = threadIdx.x;
    int qk = tid >> 7;
    int rem = tid & 127;
    int hh = rem >> 4;
    int p4 = (rem & 15) * 4;
    const ushort_t* base = rowbase + qk * D_MODEL + hh * HDIM + p4;
    ushort4 lo = *(const ushort4*)base;
    ushort4 hi = *(const ushort4*)(base + 64);
    ushort_t lov[4] = {lo.x, lo.y, lo.z, lo.w};
    ushort_t hiv[4] = {hi.x, hi.y, hi.z, hi.w};
    ushort_t lor[4], hir[4];
    #pragma unroll
    for (int j = 0; j < 4; ++j) {
        float2 cs = t2[p4 + j];
        float x1 = bf2f(lov[j]), x2 = bf2f(hiv[j]);
        lor[j] = f2bf(x1 * cs.x - x2 * cs.y);
        hir[j] = f2bf(x2 * cs.x + x1 * cs.y);
    }
    ushort_t* dst = (qk ? Kb : Qb) + ((size_t)(b * NHEAD + hh) * SEQ + s) * HDIM + p4;
    *(ushort4*)dst        = make_ushort4(lor[0], lor[1], lor[2], lor[3]);
    *(ushort4*)(dst + 64) = make_ushort4(hir[0], hir[1], hir[2], hir[3]);
}

// ---------------- V transpose: bf16 QKV V-part -> bf16 Vt [B,1024,S] -------
__global__ __launch_bounds__(256) void vtrans_kernel(
    const ushort_t* __restrict__ QKVb, ushort_t* __restrict__ Vt)
{
    __shared__ ushort_t tl[64][34];
    int s0 = blockIdx.x * 64;
    int d0 = blockIdx.y * 32;
    int b  = blockIdx.z;
    int tid = threadIdx.x;
    #pragma unroll
    for (int r = 0; r < 4; ++r) {
        int li = tid + r * 256;
        int row = li >> 4;
        int cp  = (li & 15) * 2;
        ushort2 v = *(const ushort2*)(QKVb + (size_t)(b * SEQ + s0 + row) * 3072
                                      + 2 * D_MODEL + d0 + cp);
        tl[row][cp]     = v.x;
        tl[row][cp + 1] = v.y;
    }
    __syncthreads();
    #pragma unroll
    for (int r = 0; r < 4; ++r) {
        int li = tid + r * 256;
        int drow = li >> 5;
        int sc   = (li & 31) * 2;
        ushort2 o;
        o.x = tl[sc][drow];
        o.y = tl[sc + 1][drow];
        *(ushort2*)(Vt + (size_t)(b * D_MODEL + d0 + drow) * SEQ + s0 + sc) = o;
    }
}

// ---------------- MFMA flash attention: 2 waves x 32 q-rows ----------------
// block = 128 thr; wave w owns q rows [q0 + w*32, +32) as row-groups rg=0,1.
// Each K/V fragment ds_read feeds 2 MFMAs. Round-17 balance swizzle kept.
#define PSTR 72

__global__ __launch_bounds__(128) void attn_mfma(
    const ushort_t* __restrict__ Qb, const ushort_t* __restrict__ Kb,
    const ushort_t* __restrict__ Vt, ushort_t* __restrict__ Yb)
{
    __shared__ __align__(16) ushort_t Ks[64 * 136];       // 17.4 KB
    __shared__ __align__(16) ushort_t Vts[128 * 72];      // 18.4 KB
    __shared__ __align__(16) ushort_t Pl[2][32 * PSTR];   // 9.2 KB
    int bid = blockIdx.x;
    int sflip = ((bid >> 8) ^ bid) & 1;
    int h4 = (bid >> 1) & 15;
    int qt = sflip ? 15 - h4 : h4;
    int bh = ((bid & 1) << 4) | ((bid >> 5) & 15);
    int b = bh >> 3, h = bh & 7;
    int q0 = qt * 64;
    int tid = threadIdx.x, lane = tid & 63, w = tid >> 6;   // w in 0..1
    int lr = lane & 15, g = lane >> 4;
    const float scale = 0.08838834764831845f;

    const ushort_t* Qbase = Qb + (size_t)((b * NHEAD + h) * SEQ) * HDIM;
    const ushort_t* Kbase = Kb + (size_t)((b * NHEAD + h) * SEQ) * HDIM;
    const ushort_t* Vbase = Vt + (size_t)(b * D_MODEL + h * HDIM) * SEQ;

    // Q fragments: rg=0,1 row-groups of 16
    s16x8 aq[2][4];
    #pragma unroll
    for (int rg = 0; rg < 2; ++rg)
        #pragma unroll
        for (int kc = 0; kc < 4; ++kc)
            aq[rg][kc] = *(const s16x8*)(Qbase
                + (size_t)(q0 + w * 32 + rg * 16 + lr) * HDIM + kc * 32 + g * 8);

    // staging coords (128 threads)
    int krow = tid >> 4, kc16 = tid & 15;   // K rows krow + r*8,  r<8
    int vrow = tid >> 3, vc8  = tid & 7;    // V rows vrow + r*16, r<8

    f32x4 acc_o[2][8] = {};
    float mx[2][4] = {{-INFINITY,-INFINITY,-INFINITY,-INFINITY},
                      {-INFINITY,-INFINITY,-INFINITY,-INFINITY}};
    float ls[2][4] = {};

    // prefetch tile 0
    s16x8 kreg[8], vreg[8];
    #pragma unroll
    for (int r = 0; r < 8; ++r)
        kreg[r] = *(const s16x8*)(Kbase + (size_t)(krow + r * 8) * HDIM + kc16 * 8);
    #pragma unroll
    for (int r = 0; r < 8; ++r)
        vreg[r] = *(const s16x8*)(Vbase + (size_t)(vrow + r * 16) * SEQ + vc8 * 8);

    int ntiles = q0 / 64 + 1;
    for (int t = 0; t < ntiles; ++t) {
        int j0 = t * 64;
        __syncthreads();
        #pragma unroll
        for (int r = 0; r < 8; ++r)
            *(s16x8*)&Ks[(krow + r * 8) * 136 + kc16 * 8] = kreg[r];
        #pragma unroll
        for (int r = 0; r < 8; ++r)
            *(s16x8*)&Vts[(vrow + r * 16) * 72 + vc8 * 8] = vreg[r];
        if (t + 1 < ntiles) {
            int jn = j0 + 64;
            #pragma unroll
            for (int r = 0; r < 8; ++r)
                kreg[r] = *(const s16x8*)(Kbase + (size_t)(jn + krow + r * 8) * HDIM + kc16 * 8);
            #pragma unroll
            for (int r = 0; r < 8; ++r)
                vreg[r] = *(const s16x8*)(Vbase + (size_t)(vrow + r * 16) * SEQ + jn + vc8 * 8);
        }
        __syncthreads();

        // QK^T: one K-frag read feeds both row-groups
        f32x4 sa[2][4] = {};
        __builtin_amdgcn_s_setprio(1);
        #pragma unroll
        for (int nb = 0; nb < 4; ++nb)
            #pragma unroll
            for (int kc = 0; kc < 4; ++kc) {
                s16x8 bk = *(const s16x8*)&Ks[(nb * 16 + lr) * 136 + kc * 32 + g * 8];
                #pragma unroll
                for (int rg = 0; rg < 2; ++rg)
                    sa[rg][nb] = __builtin_amdgcn_mfma_f32_16x16x32_bf16(
                        aq[rg][kc], bk, sa[rg][nb], 0, 0, 0);
            }
        __builtin_amdgcn_s_setprio(0);

        bool diag = (j0 == q0);
        float pv[2][4][4];
        #pragma unroll
        for (int rg = 0; rg < 2; ++rg)
            #pragma unroll
            for (int nb = 0; nb < 4; ++nb)
                #pragma unroll
                for (int j = 0; j < 4; ++j) {
                    float v = sa[rg][nb][j] * scale;
                    if (diag) {
                        int kv = j0 + nb * 16 + lr;
                        int qq = q0 + w * 32 + rg * 16 + g * 4 + j;
                        if (kv > qq) v = -INFINITY;
                    }
                    pv[rg][nb][j] = v;
                }
        #pragma unroll
        for (int rg = 0; rg < 2; ++rg)
            #pragma unroll
            for (int j = 0; j < 4; ++j) {
                float tm = fmaxf(fmaxf(pv[rg][0][j], pv[rg][1][j]),
                                 fmaxf(pv[rg][2][j], pv[rg][3][j]));
                #pragma unroll
                for (int o = 1; o < 16; o <<= 1) tm = fmaxf(tm, __shfl_xor(tm, o));
                if (tm > mx[rg][j] + 8.0f) {
                    float corr = expf(mx[rg][j] - tm);
                    mx[rg][j] = tm;
                    ls[rg][j] *= corr;
                    #pragma unroll
                    for (int dn = 0; dn < 8; ++dn) acc_o[rg][dn][j] *= corr;
                }
                float ts = 0.0f;
                #pragma unroll
                for (int nb = 0; nb < 4; ++nb) {
                    float e = expf(pv[rg][nb][j] - mx[rg][j]);
                    pv[rg][nb][j] = e;
                    ts += e;
                }
                #pragma unroll
                for (int o = 1; o < 16; o <<= 1) ts += __shfl_xor(ts, o);
                ls[rg][j] += ts;
            }
        // P -> wave-private LDS [32 q rows][64 kv]
        #pragma unroll
        for (int rg = 0; rg < 2; ++rg)
            #pragma unroll
            for (int nb = 0; nb < 4; ++nb)
                #pragma unroll
                for (int j = 0; j < 4; ++j)
                    Pl[w][(rg * 16 + g * 4 + j) * PSTR + nb * 16 + lr]
                        = f2bf(pv[rg][nb][j]);
        // PV: one V-frag read feeds both row-groups
        #pragma unroll
        for (int kk = 0; kk < 2; ++kk) {
            s16x8 pa[2];
            #pragma unroll
            for (int rg = 0; rg < 2; ++rg)
                pa[rg] = *(const s16x8*)&Pl[w][(rg * 16 + lr) * PSTR + kk * 32 + g * 8];
            __builtin_amdgcn_s_setprio(1);
            #pragma unroll
            for (int dn = 0; dn < 8; ++dn) {
                s16x8 bv = *(const s16x8*)&Vts[(dn * 16 + lr) * 72 + kk * 32 + g * 8];
                #pragma unroll
                for (int rg = 0; rg < 2; ++rg)
                    acc_o[rg][dn] = __builtin_amdgcn_mfma_f32_16x16x32_bf16(
                        pa[rg], bv, acc_o[rg][dn], 0, 0, 0);
            }
            __builtin_amdgcn_s_setprio(0);
        }
    }

    #pragma unroll
    for (int rg = 0; rg < 2; ++rg) {
        float il[4];
        #pragma unroll
        for (int j = 0; j < 4; ++j) il[j] = 1.0f / ls[rg][j];
        #pragma unroll
        for (int dn = 0; dn < 8; ++dn)
            #pragma unroll
            for (int j = 0; j < 4; ++j) {
                int q = q0 + w * 32 + rg * 16 + g * 4 + j;
                Yb[(size_t)(b * SEQ + q) * D_MODEL + h * HDIM + dn * 16 + lr] =
                    f2bf(acc_o[rg][dn][j] * il[j]);
            }
    }
}

// ---------------------------------------------------------------------------
extern "C" void kernel_launch(void* const* d_in, const int* in_sizes, int n_in,
                              void* d_out, int out_size, void* d_ws, size_t ws_size,
                              hipStream_t stream)
{
    const int*   tokens = (const int*)  d_in[0];
    const float* emb    = (const float*)d_in[1];
    const float* Wqkv   = (const float*)d_in[2];
    const float* bqkv   = (const float*)d_in[3];
    const float* Wo     = (const float*)d_in[4];
    const float* bo     = (const float*)d_in[5];
    const float* ln1_g  = (const float*)d_in[6];
    const float* ln1_b  = (const float*)d_in[7];
    const float* ln2_g  = (const float*)d_in[8];
    const float* ln2_b  = (const float*)d_in[9];
    const float* W1     = (const float*)d_in[10];
    const float* b1     = (const float*)d_in[11];
    const float* W2     = (const float*)d_in[12];
    const float* b2     = (const float*)d_in[13];
    const float* lnf_g  = (const float*)d_in[14];
    const float* lnf_b  = (const float*)d_in[15];
    const float* Wout   = (const float*)d_in[16];
    const float* bout   = (const float*)d_in[17];
    float* out = (float*)d_out;

    char* ws = (char*)d_ws;
    float*    X      = (float*)ws;                     // 16.78 MB
    ushort_t* Abuf   = (ushort_t*)(ws + 16777216);     // 8.39 MB
    ushort_t* QKVb   = (ushort_t*)(ws + 25165824);     // 25.17 MB
    ushort_t* Gbuf   = (ushort_t*)(ws + 25165824);     //   alias (FFN phase)
    ushort_t* Qbb    = (ushort_t*)(ws + 50331648);     // 8.39 MB
    ushort_t* Kbb    = (ushort_t*)(ws + 58720256);     // 8.39 MB
    ushort_t* Vtb    = (ushort_t*)(ws + 67108864);     // 8.39 MB
    ushort_t* WqkvT  = (ushort_t*)(ws + 75497472);     // 25.17 MB
    ushort_t* WoT    = (ushort_t*)(ws + 100663296);    // 8.39 MB
    ushort_t* W1T    = (ushort_t*)(ws + 109051904);    // 16.78 MB
    ushort_t* W2T    = (ushort_t*)(ws + 125829120);    // 16.78 MB
    ushort_t* WoutT  = (ushort_t*)(ws + 142606336);    // 65.54 MB
    float2*   RT     = (float2*)  (ws + 208142336);    // 0.52 MB -> 208.7 MB total

    const int M = MROWS, Dm = D_MODEL, F = FFN, V = VOCAB;

    rope_table_kernel<<<SEQ, 64, 0, stream>>>(RT);

    wconv<<<dim3(3*Dm/32, Dm/32, NLAYER), 256, 0, stream>>>(Wqkv, WqkvT, Dm, 3*Dm);
    wconv<<<dim3(Dm/32,   Dm/32, NLAYER), 256, 0, stream>>>(Wo,   WoT,   Dm, Dm);
    wconv<<<dim3(F/32,    Dm/32, NLAYER), 256, 0, stream>>>(W1,   W1T,   Dm, F);
    wconv<<<dim3(Dm/32,   F/32,  NLAYER), 256, 0, stream>>>(W2,   W2T,   F,  Dm);
    wconv<<<dim3(V/32,    Dm/32, 1),      256, 0, stream>>>(Wout, WoutT, Dm, V);

    embed_kernel<<<MROWS, 256, 0, stream>>>(tokens, emb, X);

    for (int L = 0; L < NLAYER; ++L) {
        ln_kernel<<<MROWS, 256, 0, stream>>>(X, ln1_g + (size_t)L*Dm, ln1_b + (size_t)L*Dm, Abuf);
        gemm_mid<0,0,1><<<dim3(M/128, 3*Dm/128), 256, 0, stream>>>(
            Abuf, WqkvT + (size_t)L*3*Dm*Dm, bqkv + (size_t)L*3*Dm, nullptr, QKVb, M, 3*Dm, Dm);
        ropeq_kernel<<<MROWS, 256, 0, stream>>>(QKVb, RT, Qbb, Kbb);
        vtrans_kernel<<<dim3(SEQ/64, Dm/32, BATCH), 256, 0, stream>>>(QKVb, Vtb);
        attn_mfma<<<BATCH*NHEAD*(SEQ/64), 128, 0, stream>>>(Qbb, Kbb, Vtb, Abuf);
        gemm_mid<0,1,0><<<dim3(M/128, Dm/128), 256, 0, stream>>>(
            Abuf, WoT + (size_t)L*Dm*Dm, bo + (size_t)L*Dm, X, nullptr, M, Dm, Dm);
        ln_kernel<<<MROWS, 256, 0, stream>>>(X, ln2_g + (size_t)L*Dm, ln2_b + (size_t)L*Dm, Abuf);
        gemm_mid<1,0,1><<<dim3(M/128, F/128), 256, 0, stream>>>(
            Abuf, W1T + (size_t)L*Dm*F, b1 + (size_t)L*F, nullptr, Gbuf, M, F, Dm);
        gemm_mid<0,1,0><<<dim3(M/128, Dm/128), 256, 0, stream>>>(
            Gbuf, W2T + (size_t)L*F*Dm, b2 + (size_t)L*Dm, X, nullptr, M, Dm, F);
    }

    ln_kernel<<<MROWS, 256, 0, stream>>>(X, lnf_g, lnf_b, Abuf);
    gemm_big<<<dim3(M/256, V/256), 512, 0, stream>>>(
        Abuf, WoutT, bout, out, M, V, Dm);
}

// Round 19
// 1348.187 us; speedup vs baseline: 1.1015x; 1.1015x over previous
//
#include <hip/hip_runtime.h>
#include <hip/hip_bf16.h>
#include <math.h>

// ---------------------------------------------------------------------------
// Round 19: revert attn to round-17 proven kernel (4 waves/256 thr, T14
// reg-prefetch, T13 defer-max, balanced work swizzle). The 2-wave re-tile
// (r18) lost to VGPR pressure + TLP loss. All else = round 17/18 (identical).
// B=4 S=1024 D=1024 H=8 Dh=128 F=2048 L=4 V=32000
// ---------------------------------------------------------------------------

#define D_MODEL 1024
#define SEQ     1024
#define BATCH   4
#define NHEAD   8
#define HDIM    128
#define FFN     2048
#define NLAYER  4
#define VOCAB   32000
#define MROWS   (BATCH*SEQ)   // 4096

typedef unsigned short ushort_t;
typedef __attribute__((ext_vector_type(8))) short s16x8;   // 8 bf16 = 4 VGPRs
typedef __attribute__((ext_vector_type(4))) float f32x4;

__device__ __forceinline__ ushort_t f2bf(float f) {
    union { float f; unsigned int u; } c; c.f = f;
    unsigned int u = c.u;
    unsigned int r = (u + 0x7FFFu + ((u >> 16) & 1u)) >> 16;
    return (ushort_t)r;
}
__device__ __forceinline__ float bf2f(ushort_t u) {
    union { unsigned int u; float f; } c; c.u = ((unsigned int)u) << 16; return c.f;
}

__device__ __forceinline__ void gload16(const void* g, void* l) {
    __builtin_amdgcn_global_load_lds(
        (const __attribute__((address_space(1))) unsigned int*)g,
        (__attribute__((address_space(3))) unsigned int*)l, 16, 0, 0);
}

__device__ __forceinline__ float gelu_exact(float x) {
    return 0.5f * x * (1.0f + erff(x * 0.70710678118654752f));
}

// ---------------- embedding gather (fp32 residual stream) ----------------
__global__ __launch_bounds__(256) void embed_kernel(
    const int* __restrict__ tokens, const float* __restrict__ emb,
    float* __restrict__ X)
{
    int row = blockIdx.x;
    int t = tokens[row];
    const float4* src = (const float4*)(emb + (size_t)t * D_MODEL);
    float4* dst = (float4*)(X + (size_t)row * D_MODEL);
    dst[threadIdx.x] = src[threadIdx.x];
}

// ---------------- layernorm: fp32 in -> bf16 out ----------------
__global__ __launch_bounds__(256) void ln_kernel(
    const float* __restrict__ X, const float* __restrict__ g,
    const float* __restrict__ b, ushort_t* __restrict__ Y)
{
    __shared__ float red[8];
    int row = blockIdx.x;
    const float4* x4 = (const float4*)(X + (size_t)row * D_MODEL);
    float4 v = x4[threadIdx.x];
    float s  = v.x + v.y + v.z + v.w;
    float ss = v.x*v.x + v.y*v.y + v.z*v.z + v.w*v.w;
    #pragma unroll
    for (int o = 32; o > 0; o >>= 1) { s += __shfl_down(s, o); ss += __shfl_down(ss, o); }
    int wid = threadIdx.x >> 6;
    if ((threadIdx.x & 63) == 0) { red[wid] = s; red[wid + 4] = ss; }
    __syncthreads();
    float tot  = red[0] + red[1] + red[2] + red[3];
    float tot2 = red[4] + red[5] + red[6] + red[7];
    float mu  = tot * (1.0f / D_MODEL);
    float var = tot2 * (1.0f / D_MODEL) - mu * mu;
    float r = rsqrtf(var + 1e-5f);
    const float4* g4 = (const float4*)g;
    const float4* b4 = (const float4*)b;
    float4 gv = g4[threadIdx.x], bv = b4[threadIdx.x];
    ushort4 o;
    o.x = f2bf((v.x - mu) * r * gv.x + bv.x);
    o.y = f2bf((v.y - mu) * r * gv.y + bv.y);
    o.z = f2bf((v.z - mu) * r * gv.z + bv.z);
    o.w = f2bf((v.w - mu) * r * gv.w + bv.w);
    ((ushort4*)(Y + (size_t)row * D_MODEL))[threadIdx.x] = o;
}

// ---------------- weight fp32 [K][N] -> bf16 transposed [N][K] -------------
__global__ __launch_bounds__(256) void wconv(
    const float* __restrict__ W, ushort_t* __restrict__ Wt, int K, int N)
{
    __shared__ float t[32][33];
    const float* Wl = W + (size_t)blockIdx.z * K * N;
    ushort_t* Wtl = Wt + (size_t)blockIdx.z * K * N;
    int k0 = blockIdx.y * 32, n0 = blockIdx.x * 32;
    int tid = threadIdx.x;
    int r = tid >> 3, c4 = (tid & 7) * 4;
    float4 v = *(const float4*)(Wl + (size_t)(k0 + r) * N + n0 + c4);
    t[r][c4+0] = v.x; t[r][c4+1] = v.y; t[r][c4+2] = v.z; t[r][c4+3] = v.w;
    __syncthreads();
    ushort4 o;
    o.x = f2bf(t[c4+0][r]); o.y = f2bf(t[c4+1][r]);
    o.z = f2bf(t[c4+2][r]); o.w = f2bf(t[c4+3][r]);
    *(ushort4*)(Wtl + (size_t)(n0 + r) * K + k0 + c4) = o;
}

// ---------------- 128x128 pipelined counted-vmcnt GEMM + T2 (layers) -------
template<int ACT, int BETA, int OBF>
__global__ __launch_bounds__(256) void gemm_mid(
    const ushort_t* __restrict__ A, const ushort_t* __restrict__ Bt,
    const float* __restrict__ bias, float* __restrict__ Cf,
    ushort_t* __restrict__ Cb, int M, int N, int K)
{
    __shared__ __align__(16) ushort_t As[2][128 * 64];   // 32 KB
    __shared__ __align__(16) ushort_t Bs[2][128 * 64];   // 32 KB
    int tid = threadIdx.x, lane = tid & 63, w = tid >> 6;
    int wm = w >> 1, wn = w & 1;
    int m0 = blockIdx.x * 128, n0 = blockIdx.y * 128;
    int lr = lane & 15, kg = lane >> 4;
    const int NKT = K / 64;

    f32x4 acc[4][4] = {};

    int srow = w * 8 + (lane >> 3);                       // 0..31
    int scol = (((lane & 7) ^ ((lane >> 3) & 7))) * 8;    // T2 pre-swizzled src

    int rsw = lr & 7;
    int ch0 = (kg    ) ^ rsw;
    int ch1 = (kg + 4) ^ rsw;

#define STAGE_A(db, ht, ktile) do { \
    const ushort_t* s_ = A + (size_t)(m0 + (ht) * 64 + srow) * K + (size_t)(ktile) * 64 + scol; \
    gload16(s_,                  &As[db][((ht) * 64 + w * 8) * 64]); \
    gload16(s_ + (size_t)32 * K, &As[db][((ht) * 64 + 32 + w * 8) * 64]); \
} while (0)
#define STAGE_B(db, ht, ktile) do { \
    const ushort_t* s_ = Bt + (size_t)(n0 + (ht) * 64 + srow) * K + (size_t)(ktile) * 64 + scol; \
    gload16(s_,                  &Bs[db][((ht) * 64 + w * 8) * 64]); \
    gload16(s_ + (size_t)32 * K, &Bs[db][((ht) * 64 + 32 + w * 8) * 64]); \
} while (0)
#define SBAR() do { __builtin_amdgcn_sched_barrier(0); \
    __builtin_amdgcn_s_barrier(); __builtin_amdgcn_sched_barrier(0); } while (0)

    STAGE_A(0, 0, 0); STAGE_A(0, 1, 0); STAGE_B(0, 0, 0); STAGE_B(0, 1, 0);
    STAGE_A(1, 0, 1);
    asm volatile("s_waitcnt vmcnt(2)" ::: "memory");
    SBAR();

    for (int kt = 0; kt < NKT; ++kt) {
        int d = kt & 1, dn = d ^ 1;
        const ushort_t* pa0 = &As[d][(wm * 64 + lr) * 64 + ch0 * 8];
        const ushort_t* pa1 = &As[d][(wm * 64 + lr) * 64 + ch1 * 8];
        const ushort_t* pb0 = &Bs[d][(wn * 64 + lr) * 64 + ch0 * 8];
        const ushort_t* pb1 = &Bs[d][(wn * 64 + lr) * 64 + ch1 * 8];
        s16x8 a[4][2], b[4][2];

        #pragma unroll
        for (int mi = 0; mi < 4; ++mi) {
            a[mi][0] = *(const s16x8*)(pa0 + mi * 1024);
            a[mi][1] = *(const s16x8*)(pa1 + mi * 1024);
        }
        #pragma unroll
        for (int ni = 0; ni < 4; ++ni) {
            b[ni][0] = *(const s16x8*)(pb0 + ni * 1024);
            b[ni][1] = *(const s16x8*)(pb1 + ni * 1024);
        }
        if (kt + 1 < NKT) STAGE_A(dn, 1, kt + 1);
        __builtin_amdgcn_sched_barrier(0);

        __builtin_amdgcn_s_setprio(1);
        #pragma unroll
        for (int mi = 0; mi < 2; ++mi)
            #pragma unroll
            for (int ni = 0; ni < 2; ++ni)
                #pragma unroll
                for (int kk = 0; kk < 2; ++kk)
                    acc[mi][ni] = __builtin_amdgcn_mfma_f32_16x16x32_bf16(
                        a[mi][kk], b[ni][kk], acc[mi][ni], 0, 0, 0);
        __builtin_amdgcn_s_setprio(0);
        __builtin_amdgcn_sched_barrier(0);
        if (kt + 1 < NKT) STAGE_B(dn, 0, kt + 1);
        __builtin_amdgcn_sched_barrier(0);

        __builtin_amdgcn_s_setprio(1);
        #pragma unroll
        for (int mi = 0; mi < 2; ++mi)
            #pragma unroll
            for (int ni = 2; ni < 4; ++ni)
                #pragma unroll
                for (int kk = 0; kk < 2; ++kk)
                    acc[mi][ni] = __builtin_amdgcn_mfma_f32_16x16x32_bf16(
                        a[mi][kk], b[ni][kk], acc[mi][ni], 0, 0, 0);
        __builtin_amdgcn_s_setprio(0);
        __builtin_amdgcn_sched_barrier(0);
        if (kt + 1 < NKT) STAGE_B(dn, 1, kt + 1);
        __builtin_amdgcn_sched_barrier(0);

        __builtin_amdgcn_s_setprio(1);
        #pragma unroll
        for (int mi = 2; mi < 4; ++mi)
            #pragma unroll
            for (int ni = 0; ni < 2; ++ni)
                #pragma unroll
                for (int kk = 0; kk < 2; ++kk)
                    acc[mi][ni] = __builtin_amdgcn_mfma_f32_16x16x32_bf16(
                        a[mi][kk], b[ni][kk], acc[mi][ni], 0, 0, 0);
        __builtin_amdgcn_s_setprio(0);

        asm volatile("s_waitcnt lgkmcnt(0)" ::: "memory");
        SBAR();
        if (kt + 2 < NKT) STAGE_A(d, 0, kt + 2);
        __builtin_amdgcn_sched_barrier(0);

        __builtin_amdgcn_s_setprio(1);
        #pragma unroll
        for (int mi = 2; mi < 4; ++mi)
            #pragma unroll
            for (int ni = 2; ni < 4; ++ni)
                #pragma unroll
                for (int kk = 0; kk < 2; ++kk)
                    acc[mi][ni] = __builtin_amdgcn_mfma_f32_16x16x32_bf16(
                        a[mi][kk], b[ni][kk], acc[mi][ni], 0, 0, 0);
        __builtin_amdgcn_s_setprio(0);

        if (kt + 2 < NKT) {
            asm volatile("s_waitcnt vmcnt(2)" ::: "memory");
        } else {
            asm volatile("s_waitcnt vmcnt(0)" ::: "memory");
        }
        SBAR();
    }
#undef STAGE_A
#undef STAGE_B
#undef SBAR

    #pragma unroll
    for (int mi = 0; mi < 4; ++mi) {
        int rbase = m0 + wm * 64 + mi * 16 + kg * 4;
        #pragma unroll
        for (int ni = 0; ni < 4; ++ni) {
            int col = n0 + wn * 64 + ni * 16 + lr;
            float bz = bias[col];
            f32x4 v = acc[mi][ni];
            #pragma unroll
            for (int j = 0; j < 4; ++j) {
                float x = v[j] + bz;
                if (ACT == 1) x = gelu_exact(x);
                size_t off = (size_t)(rbase + j) * N + col;
                if (OBF) {
                    Cb[off] = f2bf(x);
                } else {
                    if (BETA) x += Cf[off];
                    Cf[off] = x;
                }
            }
        }
    }
}

// ---------------- 256x256 pipelined counted-vmcnt GEMM + T2 (logits) -------
__global__ __launch_bounds__(512) void gemm_big(
    const ushort_t* __restrict__ A, const ushort_t* __restrict__ Bt,
    const float* __restrict__ bias, float* __restrict__ C,
    int M, int N, int K)
{
    __shared__ __align__(16) ushort_t As[2][256 * 64];   // 64 KB
    __shared__ __align__(16) ushort_t Bs[2][256 * 64];   // 64 KB
    int tid = threadIdx.x, lane = tid & 63, w = tid >> 6;
    int wm = w >> 2, wn = w & 3;
    int m0 = blockIdx.x * 256, n0 = blockIdx.y * 256;
    int lr = lane & 15, kg = lane >> 4;
    const int NKT = K / 64;

    f32x4 acc[8][4] = {};

    int srow = w * 8 + (lane >> 3);
    int scol = (((lane & 7) ^ ((lane >> 3) & 7))) * 8;

    int rsw = lr & 7;
    int ch0 = (kg    ) ^ rsw;
    int ch1 = (kg + 4) ^ rsw;

#define STAGE_A(db, ht, ktile) do { \
    const ushort_t* s_ = A + (size_t)(m0 + (ht) * 128 + srow) * K + (size_t)(ktile) * 64 + scol; \
    gload16(s_,                  &As[db][((ht) * 128 + w * 8) * 64]); \
    gload16(s_ + (size_t)64 * K, &As[db][((ht) * 128 + 64 + w * 8) * 64]); \
} while (0)
#define STAGE_B(db, ht, ktile) do { \
    const ushort_t* s_ = Bt + (size_t)(n0 + (ht) * 128 + srow) * K + (size_t)(ktile) * 64 + scol; \
    gload16(s_,                  &Bs[db][((ht) * 128 + w * 8) * 64]); \
    gload16(s_ + (size_t)64 * K, &Bs[db][((ht) * 128 + 64 + w * 8) * 64]); \
} while (0)
#define SBAR() do { __builtin_amdgcn_sched_barrier(0); \
    __builtin_amdgcn_s_barrier(); __builtin_amdgcn_sched_barrier(0); } while (0)

    STAGE_A(0, 0, 0); STAGE_A(0, 1, 0); STAGE_B(0, 0, 0); STAGE_B(0, 1, 0);
    STAGE_A(1, 0, 1);
    asm volatile("s_waitcnt vmcnt(2)" ::: "memory");
    SBAR();

    for (int kt = 0; kt < NKT; ++kt) {
        int d = kt & 1, dn = d ^ 1;
        const ushort_t* pa0 = &As[d][(wm * 128 + lr) * 64 + ch0 * 8];
        const ushort_t* pa1 = &As[d][(wm * 128 + lr) * 64 + ch1 * 8];
        const ushort_t* pb0 = &Bs[d][(wn * 64  + lr) * 64 + ch0 * 8];
        const ushort_t* pb1 = &Bs[d][(wn * 64  + lr) * 64 + ch1 * 8];
        s16x8 a03[4][2], a47[4][2], b01[2][2], b23[2][2];

        #pragma unroll
        for (int mi = 0; mi < 4; ++mi) {
            a03[mi][0] = *(const s16x8*)(pa0 + mi * 1024);
            a03[mi][1] = *(const s16x8*)(pa1 + mi * 1024);
        }
        #pragma unroll
        for (int ni = 0; ni < 2; ++ni) {
            b01[ni][0] = *(const s16x8*)(pb0 + ni * 1024);
            b01[ni][1] = *(const s16x8*)(pb1 + ni * 1024);
        }
        #pragma unroll
        for (int ni = 0; ni < 2; ++ni) {
            b23[ni][0] = *(const s16x8*)(pb0 + (2 + ni) * 1024);
            b23[ni][1] = *(const s16x8*)(pb1 + (2 + ni) * 1024);
        }
        #pragma unroll
        for (int mi = 0; mi < 4; ++mi) {
            a47[mi][0] = *(const s16x8*)(pa0 + (4 + mi) * 1024);
            a47[mi][1] = *(const s16x8*)(pa1 + (4 + mi) * 1024);
        }
        if (kt + 1 < NKT) STAGE_A(dn, 1, kt + 1);
        __builtin_amdgcn_sched_barrier(0);

        __builtin_amdgcn_s_setprio(1);
        #pragma unroll
        for (int mi = 0; mi < 4; ++mi)
            #pragma unroll
            for (int ni = 0; ni < 2; ++ni)
                #pragma unroll
                for (int kk = 0; kk < 2; ++kk)
                    acc[mi][ni] = __builtin_amdgcn_mfma_f32_16x16x32_bf16(
                        a03[mi][kk], b01[ni][kk], acc[mi][ni], 0, 0, 0);
        __builtin_amdgcn_s_setprio(0);
        __builtin_amdgcn_sched_barrier(0);
        if (kt + 1 < NKT) STAGE_B(dn, 0, kt + 1);
        __builtin_amdgcn_sched_barrier(0);

        __builtin_amdgcn_s_setprio(1);
        #pragma unroll
        for (int mi = 0; mi < 4; ++mi)
            #pragma unroll
            for (int ni = 0; ni < 2; ++ni)
                #pragma unroll
                for (int kk = 0; kk < 2; ++kk)
                    acc[mi][2 + ni] = __builtin_amdgcn_mfma_f32_16x16x32_bf16(
                        a03[mi][kk], b23[ni][kk], acc[mi][2 + ni], 0, 0, 0);
        __builtin_amdgcn_s_setprio(0);
        __builtin_amdgcn_sched_barrier(0);
        if (kt + 1 < NKT) STAGE_B(dn, 1, kt + 1);
        __builtin_amdgcn_sched_barrier(0);

        __builtin_amdgcn_s_setprio(1);
        #pragma unroll
        for (int mi = 0; mi < 4; ++mi)
            #pragma unroll
            for (int ni = 0; ni < 2; ++ni)
                #pragma unroll
                for (int kk = 0; kk < 2; ++kk)
                    acc[4 + mi][ni] = __builtin_amdgcn_mfma_f32_16x16x32_bf16(
                        a47[mi][kk], b01[ni][kk], acc[4 + mi][ni], 0, 0, 0);
        __builtin_amdgcn_s_setprio(0);

        asm volatile("s_waitcnt lgkmcnt(0)" ::: "memory");
        SBAR();
        if (kt + 2 < NKT) STAGE_A(d, 0, kt + 2);
        __builtin_amdgcn_sched_barrier(0);

        __builtin_amdgcn_s_setprio(1);
        #pragma unroll
        for (int mi = 0; mi < 4; ++mi)
            #pragma unroll
            for (int ni = 0; ni < 2; ++ni)
                #pragma unroll
                for (int kk = 0; kk < 2; ++kk)
                    acc[4 + mi][2 + ni] = __builtin_amdgcn_mfma_f32_16x16x32_bf16(
                        a47[mi][kk], b23[ni][kk], acc[4 + mi][2 + ni], 0, 0, 0);
        __builtin_amdgcn_s_setprio(0);

        if (kt + 2 < NKT) {
            asm volatile("s_waitcnt vmcnt(2)" ::: "memory");
        } else {
            asm volatile("s_waitcnt vmcnt(0)" ::: "memory");
        }
        SBAR();
    }
#undef STAGE_A
#undef STAGE_B
#undef SBAR

    #pragma unroll
    for (int mi = 0; mi < 8; ++mi) {
        int rbase = m0 + wm * 128 + mi * 16 + kg * 4;
        #pragma unroll
        for (int ni = 0; ni < 4; ++ni) {
            int col = n0 + wn * 64 + ni * 16 + lr;
            float bz = bias[col];
            f32x4 v = acc[mi][ni];
            #pragma unroll
            for (int j = 0; j < 4; ++j)
                C[(size_t)(rbase + j) * N + col] = v[j] + bz;
        }
    }
}

// ---------------- RoPE cos/sin table: [S][64] float2 (cos, sin) ------------
__global__ __launch_bounds__(64) void rope_table_kernel(float2* __restrict__ RT)
{
    int s = blockIdx.x, p = threadIdx.x;
    float inv = expf(-0.14391156831212788f * (float)p);   // 10000^(-p/64)
    float ang = (float)s * inv;
    float sn, c;
    sincosf(ang, &sn, &c);
    RT[s * 64 + p] = make_float2(c, sn);
}

// ---------------- RoPE: bf16 QKV -> bf16 Qb, Kb [B,H,S,Dh] (table) ---------
__global__ __launch_bounds__(256) void ropeq_kernel(
    const ushort_t* __restrict__ QKVb, const float2* __restrict__ RT,
    ushort_t* __restrict__ Qb, ushort_t* __restrict__ Kb)
{
    int m = blockIdx.x;
    int b = m >> 10, s = m & (SEQ - 1);
    const ushort_t* rowbase = QKVb + (size_t)m * (3 * D_MODEL);
    const float2* t2 = RT + s * 64;
    int tid = threadIdx.x;
    int qk = tid >> 7;
    int rem = tid & 127;
    int hh = rem >> 4;
    int p4 = (rem & 15) * 4;
    const ushort_t* base = rowbase + qk * D_MODEL + hh * HDIM + p4;
    ushort4 lo = *(const ushort4*)base;
    ushort4 hi = *(const ushort4*)(base + 64);
    ushort_t lov[4] = {lo.x, lo.y, lo.z, lo.w};
    ushort_t hiv[4] = {hi.x, hi.y, hi.z, hi.w};
    ushort_t lor[4], hir[4];
    #pragma unroll
    for (int j = 0; j < 4; ++j) {
        float2 cs = t2[p4 + j];
        float x1 = bf2f(lov[j]), x2 = bf2f(hiv[j]);
        lor[j] = f2bf(x1 * cs.x - x2 * cs.y);
        hir[j] = f2bf(x2 * cs.x + x1 * cs.y);
    }
    ushort_t* dst = (qk ? Kb : Qb) + ((size_t)(b * NHEAD + hh) * SEQ + s) * HDIM + p4;
    *(ushort4*)dst        = make_ushort4(lor[0], lor[1], lor[2], lor[3]);
    *(ushort4*)(dst + 64) = make_ushort4(hir[0], hir[1], hir[2], hir[3]);
}

// ---------------- V transpose: bf16 QKV V-part -> bf16 Vt [B,1024,S] -------
__global__ __launch_bounds__(256) void vtrans_kernel(
    const ushort_t* __restrict__ QKVb, ushort_t* __restrict__ Vt)
{
    __shared__ ushort_t tl[64][34];
    int s0 = blockIdx.x * 64;
    int d0 = blockIdx.y * 32;
    int b  = blockIdx.z;
    int tid = threadIdx.x;
    #pragma unroll
    for (int r = 0; r < 4; ++r) {
        int li = tid + r * 256;
        int row = li >> 4;
        int cp  = (li & 15) * 2;
        ushort2 v = *(const ushort2*)(QKVb + (size_t)(b * SEQ + s0 + row) * 3072
                                      + 2 * D_MODEL + d0 + cp);
        tl[row][cp]     = v.x;
        tl[row][cp + 1] = v.y;
    }
    __syncthreads();
    #pragma unroll
    for (int r = 0; r < 4; ++r) {
        int li = tid + r * 256;
        int drow = li >> 5;
        int sc   = (li & 31) * 2;
        ushort2 o;
        o.x = tl[sc][drow];
        o.y = tl[sc + 1][drow];
        *(ushort2*)(Vt + (size_t)(b * D_MODEL + d0 + drow) * SEQ + s0 + sc) = o;
    }
}

// ---------------- MFMA flash attention (round-17 proven) -------------------
// block = (b,h,64-row q-tile) via balanced bijective swizzle; 4 waves;
// T14 reg-prefetch staging; T13 defer-max (THR=8).
#define PSTR 72

__global__ __launch_bounds__(256) void attn_mfma(
    const ushort_t* __restrict__ Qb, const ushort_t* __restrict__ Kb,
    const ushort_t* __restrict__ Vt, ushort_t* __restrict__ Yb)
{
    __shared__ __align__(16) ushort_t Ks[64 * 136];
    __shared__ __align__(16) ushort_t Vts[128 * 72];
    __shared__ __align__(16) ushort_t Pl[4][16 * PSTR];
    int bid = blockIdx.x;
    int sflip = ((bid >> 8) ^ bid) & 1;
    int h4 = (bid >> 1) & 15;
    int qt = sflip ? 15 - h4 : h4;
    int bh = ((bid & 1) << 4) | ((bid >> 5) & 15);   // 0..31
    int b = bh >> 3, h = bh & 7;
    int q0 = qt * 64;
    int tid = threadIdx.x, lane = tid & 63, w = tid >> 6;
    int lr = lane & 15, g = lane >> 4;
    const float scale = 0.08838834764831845f;

    const ushort_t* Qbase = Qb + (size_t)((b * NHEAD + h) * SEQ) * HDIM;
    const ushort_t* Kbase = Kb + (size_t)((b * NHEAD + h) * SEQ) * HDIM;
    const ushort_t* Vbase = Vt + (size_t)(b * D_MODEL + h * HDIM) * SEQ;

    s16x8 aq[4];
    #pragma unroll
    for (int kc = 0; kc < 4; ++kc)
        aq[kc] = *(const s16x8*)(Qbase + (size_t)(q0 + w * 16 + lr) * HDIM + kc * 32 + g * 8);

    int krow = tid >> 4, kc16 = tid & 15;
    int vrow = tid >> 3, vc8  = tid & 7;

    f32x4 acc_o[8] = {};
    float mx[4] = {-INFINITY, -INFINITY, -INFINITY, -INFINITY};
    float ls[4] = {};

    s16x8 kreg[4], vreg[4];
    #pragma unroll
    for (int r = 0; r < 4; ++r)
        kreg[r] = *(const s16x8*)(Kbase + (size_t)(krow + r * 16) * HDIM + kc16 * 8);
    #pragma unroll
    for (int r = 0; r < 4; ++r)
        vreg[r] = *(const s16x8*)(Vbase + (size_t)(vrow + r * 32) * SEQ + vc8 * 8);

    int ntiles = q0 / 64 + 1;
    for (int t = 0; t < ntiles; ++t) {
        int j0 = t * 64;
        __syncthreads();
        #pragma unroll
        for (int r = 0; r < 4; ++r)
            *(s16x8*)&Ks[(krow + r * 16) * 136 + kc16 * 8] = kreg[r];
        #pragma unroll
        for (int r = 0; r < 4; ++r)
            *(s16x8*)&Vts[(vrow + r * 32) * 72 + vc8 * 8] = vreg[r];
        if (t + 1 < ntiles) {
            int jn = j0 + 64;
            #pragma unroll
            for (int r = 0; r < 4; ++r)
                kreg[r] = *(const s16x8*)(Kbase + (size_t)(jn + krow + r * 16) * HDIM + kc16 * 8);
            #pragma unroll
            for (int r = 0; r < 4; ++r)
                vreg[r] = *(const s16x8*)(Vbase + (size_t)(vrow + r * 32) * SEQ + jn + vc8 * 8);
        }
        __syncthreads();

        f32x4 sa[4] = {};
        __builtin_amdgcn_s_setprio(1);
        #pragma unroll
        for (int nb = 0; nb < 4; ++nb)
            #pragma unroll
            for (int kc = 0; kc < 4; ++kc) {
                s16x8 bk = *(const s16x8*)&Ks[(nb * 16 + lr) * 136 + kc * 32 + g * 8];
                sa[nb] = __builtin_amdgcn_mfma_f32_16x16x32_bf16(aq[kc], bk, sa[nb], 0, 0, 0);
            }
        __builtin_amdgcn_s_setprio(0);

        bool diag = (j0 == q0);
        float pv[4][4];
        #pragma unroll
        for (int nb = 0; nb < 4; ++nb)
            #pragma unroll
            for (int j = 0; j < 4; ++j) {
                float v = sa[nb][j] * scale;
                if (diag) {
                    int kv = j0 + nb * 16 + lr;
                    int qq = q0 + w * 16 + g * 4 + j;
                    if (kv > qq) v = -INFINITY;
                }
                pv[nb][j] = v;
            }
        #pragma unroll
        for (int j = 0; j < 4; ++j) {
            float tm = fmaxf(fmaxf(pv[0][j], pv[1][j]), fmaxf(pv[2][j], pv[3][j]));
            #pragma unroll
            for (int o = 1; o < 16; o <<= 1) tm = fmaxf(tm, __shfl_xor(tm, o));
            if (tm > mx[j] + 8.0f) {
                float corr = expf(mx[j] - tm);
                mx[j] = tm;
                ls[j] *= corr;
                #pragma unroll
                for (int dn = 0; dn < 8; ++dn) acc_o[dn][j] *= corr;
            }
            float ts = 0.0f;
            #pragma unroll
            for (int nb = 0; nb < 4; ++nb) {
                float e = expf(pv[nb][j] - mx[j]);
                pv[nb][j] = e;
                ts += e;
            }
            #pragma unroll
            for (int o = 1; o < 16; o <<= 1) ts += __shfl_xor(ts, o);
            ls[j] += ts;
        }
        #pragma unroll
        for (int nb = 0; nb < 4; ++nb)
            #pragma unroll
            for (int j = 0; j < 4; ++j)
                Pl[w][(g * 4 + j) * PSTR + nb * 16 + lr] = f2bf(pv[nb][j]);
        #pragma unroll
        for (int kk = 0; kk < 2; ++kk) {
            s16x8 pa = *(const s16x8*)&Pl[w][lr * PSTR + kk * 32 + g * 8];
            __builtin_amdgcn_s_setprio(1);
            #pragma unroll
            for (int dn = 0; dn < 8; ++dn) {
                s16x8 bv = *(const s16x8*)&Vts[(dn * 16 + lr) * 72 + kk * 32 + g * 8];
                acc_o[dn] = __builtin_amdgcn_mfma_f32_16x16x32_bf16(pa, bv, acc_o[dn], 0, 0, 0);
            }
            __builtin_amdgcn_s_setprio(0);
        }
    }

    float il[4];
    #pragma unroll
    for (int j = 0; j < 4; ++j) il[j] = 1.0f / ls[j];
    #pragma unroll
    for (int dn = 0; dn < 8; ++dn)
        #pragma unroll
        for (int j = 0; j < 4; ++j) {
            int q = q0 + w * 16 + g * 4 + j;
            Yb[(size_t)(b * SEQ + q) * D_MODEL + h * HDIM + dn * 16 + lr] =
                f2bf(acc_o[dn][j] * il[j]);
        }
}

// ---------------------------------------------------------------------------
extern "C" void kernel_launch(void* const* d_in, const int* in_sizes, int n_in,
                              void* d_out, int out_size, void* d_ws, size_t ws_size,
                              hipStream_t stream)
{
    const int*   tokens = (const int*)  d_in[0];
    const float* emb    = (const float*)d_in[1];
    const float* Wqkv   = (const float*)d_in[2];
    const float* bqkv   = (const float*)d_in[3];
    const float* Wo     = (const float*)d_in[4];
    const float* bo     = (const float*)d_in[5];
    const float* ln1_g  = (const float*)d_in[6];
    const float* ln1_b  = (const float*)d_in[7];
    const float* ln2_g  = (const float*)d_in[8];
    const float* ln2_b  = (const float*)d_in[9];
    const float* W1     = (const float*)d_in[10];
    const float* b1     = (const float*)d_in[11];
    const float* W2     = (const float*)d_in[12];
    const float* b2     = (const float*)d_in[13];
    const float* lnf_g  = (const float*)d_in[14];
    const float* lnf_b  = (const float*)d_in[15];
    const float* Wout   = (const float*)d_in[16];
    const float* bout   = (const float*)d_in[17];
    float* out = (float*)d_out;

    char* ws = (char*)d_ws;
    float*    X      = (float*)ws;                     // 16.78 MB
    ushort_t* Abuf   = (ushort_t*)(ws + 16777216);     // 8.39 MB
    ushort_t* QKVb   = (ushort_t*)(ws + 25165824);     // 25.17 MB
    ushort_t* Gbuf   = (ushort_t*)(ws + 25165824);     //   alias (FFN phase)
    ushort_t* Qbb    = (ushort_t*)(ws + 50331648);     // 8.39 MB
    ushort_t* Kbb    = (ushort_t*)(ws + 58720256);     // 8.39 MB
    ushort_t* Vtb    = (ushort_t*)(ws + 67108864);     // 8.39 MB
    ushort_t* WqkvT  = (ushort_t*)(ws + 75497472);     // 25.17 MB
    ushort_t* WoT    = (ushort_t*)(ws + 100663296);    // 8.39 MB
    ushort_t* W1T    = (ushort_t*)(ws + 109051904);    // 16.78 MB
    ushort_t* W2T    = (ushort_t*)(ws + 125829120);    // 16.78 MB
    ushort_t* WoutT  = (ushort_t*)(ws + 142606336);    // 65.54 MB
    float2*   RT     = (float2*)  (ws + 208142336);    // 0.52 MB -> 208.7 MB total

    const int M = MROWS, Dm = D_MODEL, F = FFN, V = VOCAB;

    rope_table_kernel<<<SEQ, 64, 0, stream>>>(RT);

    wconv<<<dim3(3*Dm/32, Dm/32, NLAYER), 256, 0, stream>>>(Wqkv, WqkvT, Dm, 3*Dm);
    wconv<<<dim3(Dm/32,   Dm/32, NLAYER), 256, 0, stream>>>(Wo,   WoT,   Dm, Dm);
    wconv<<<dim3(F/32,    Dm/32, NLAYER), 256, 0, stream>>>(W1,   W1T,   Dm, F);
    wconv<<<dim3(Dm/32,   F/32,  NLAYER), 256, 0, stream>>>(W2,   W2T,   F,  Dm);
    wconv<<<dim3(V/32,    Dm/32, 1),      256, 0, stream>>>(Wout, WoutT, Dm, V);

    embed_kernel<<<MROWS, 256, 0, stream>>>(tokens, emb, X);

    for (int L = 0; L < NLAYER; ++L) {
        ln_kernel<<<MROWS, 256, 0, stream>>>(X, ln1_g + (size_t)L*Dm, ln1_b + (size_t)L*Dm, Abuf);
        gemm_mid<0,0,1><<<dim3(M/128, 3*Dm/128), 256, 0, stream>>>(
            Abuf, WqkvT + (size_t)L*3*Dm*Dm, bqkv + (size_t)L*3*Dm, nullptr, QKVb, M, 3*Dm, Dm);
        ropeq_kernel<<<MROWS, 256, 0, stream>>>(QKVb, RT, Qbb, Kbb);
        vtrans_kernel<<<dim3(SEQ/64, Dm/32, BATCH), 256, 0, stream>>>(QKVb, Vtb);
        attn_mfma<<<BATCH*NHEAD*(SEQ/64), 256, 0, stream>>>(Qbb, Kbb, Vtb, Abuf);
        gemm_mid<0,1,0><<<dim3(M/128, Dm/128), 256, 0, stream>>>(
            Abuf, WoT + (size_t)L*Dm*Dm, bo + (size_t)L*Dm, X, nullptr, M, Dm, Dm);
        ln_kernel<<<MROWS, 256, 0, stream>>>(X, ln2_g + (size_t)L*Dm, ln2_b + (size_t)L*Dm, Abuf);
        gemm_mid<1,0,1><<<dim3(M/128, F/128), 256, 0, stream>>>(
            Abuf, W1T + (size_t)L*Dm*F, b1 + (size_t)L*F, nullptr, Gbuf, M, F, Dm);
        gemm_mid<0,1,0><<<dim3(M/128, Dm/128), 256, 0, stream>>>(
            Gbuf, W2T + (size_t)L*F*Dm, b2 + (size_t)L*Dm, X, nullptr, M, Dm, F);
    }

    ln_kernel<<<MROWS, 256, 0, stream>>>(X, lnf_g, lnf_b, Abuf);
    gemm_big<<<dim3(M/256, V/256), 512, 0, stream>>>(
        Abuf, WoutT, bout, out, M, V, Dm);
}